// Round 7
// baseline (206.320 us; speedup 1.0000x reference)
//
#include <hip/hip_runtime.h>
#include <hip/hip_bf16.h>

#define DD 256
#define CC 104

typedef __bf16 bf16x8 __attribute__((ext_vector_type(8)));
typedef float  f32x4  __attribute__((ext_vector_type(4)));

__device__ inline float bu2f(unsigned short u) {
    return __uint_as_float(((unsigned)u) << 16);
}
__device__ inline unsigned short f2bu(float f) {
    __hip_bfloat16 h = __float2bfloat16(f);
    return *reinterpret_cast<unsigned short*>(&h);
}

// ---------------------------------------------------------------------------
// Kernel 1: merged prep (edge tokens + segment bounds) and fp32->bf16 convert
// ---------------------------------------------------------------------------
__global__ void prep_convert_kernel(
    const int* __restrict__ token_id,
    const int* __restrict__ src_idx,
    const int* __restrict__ dst_idx,
    int* __restrict__ seg_start,
    int* __restrict__ seg_end,
    int* __restrict__ edge_tok,
    int E, int prep_blocks,
    const float* __restrict__ emb,
    const float* __restrict__ W,
    const float* __restrict__ Wc,
    __hip_bfloat16* __restrict__ embb,
    __hip_bfloat16* __restrict__ Wb,
    __hip_bfloat16* __restrict__ Wcb,
    int nE4)
{
    if ((int)blockIdx.x < prep_blocks) {
        int e = blockIdx.x * blockDim.x + threadIdx.x;
        if (e >= E) return;
        int d = dst_idx[e];
        edge_tok[e] = token_id[src_idx[e]];
        if (e == 0 || dst_idx[e - 1] != d) seg_start[d] = e;
        if (e == E - 1 || dst_idx[e + 1] != d) seg_end[d] = e + 1;
        return;
    }
    const int nW4  = DD * DD / 4;
    const int nWc4 = 128 * DD / 4;
    int i = (blockIdx.x - prep_blocks) * blockDim.x + threadIdx.x;
    float4 v;
    __hip_bfloat16* dst;
    if (i < nE4) {
        v = ((const float4*)emb)[i];
        dst = embb + (size_t)i * 4;
    } else if (i < nE4 + nW4) {
        int j = i - nE4;
        v = ((const float4*)W)[j];
        dst = Wb + (size_t)j * 4;
    } else if (i < nE4 + nW4 + nWc4) {
        int j = i - nE4 - nW4;
        v = (j < CC * DD / 4) ? ((const float4*)Wc)[j]
                              : make_float4(0.f, 0.f, 0.f, 0.f);
        dst = Wcb + (size_t)j * 4;
    } else return;
    ushort4 o;
    o.x = f2bu(v.x); o.y = f2bu(v.y); o.z = f2bu(v.z); o.w = f2bu(v.w);
    *(ushort4*)dst = o;
}

// ---------------------------------------------------------------------------
// Kernel 2: segment sum. One wave per dst; half-wave h covers edges
// s+h, s+h+2, ...; 32 lanes x 16B span the 512B bf16 row. Unroll 4 ->
// 4 row-gathers in flight per thread (R6: only 2 -> latency-bound 8.7TB/s).
// ---------------------------------------------------------------------------
__global__ void seg_sum_kernel(const __hip_bfloat16* __restrict__ embb,
                               const int* __restrict__ edge_tok,
                               const int* __restrict__ seg_start,
                               const int* __restrict__ seg_end,
                               __hip_bfloat16* __restrict__ childb,
                               int n_dst)
{
    int w = (blockIdx.x * blockDim.x + threadIdx.x) >> 6;
    int lane = threadIdx.x & 63;
    if (w >= n_dst) return;
    int h   = lane >> 5;
    int l32 = lane & 31;
    int s = seg_start[w];
    int e = seg_end[w] - 1;          // exclude last edge (RNN current input)
    float acc[8] = {0.f,0.f,0.f,0.f,0.f,0.f,0.f,0.f};

    int i = s + h;
    for (; i + 6 < e; i += 8) {      // 4 edges per half-wave in flight
        int t0 = edge_tok[i];
        int t1 = edge_tok[i + 2];
        int t2 = edge_tok[i + 4];
        int t3 = edge_tok[i + 6];
        uint4 u0 = *(const uint4*)(embb + (size_t)t0 * DD + l32 * 8);
        uint4 u1 = *(const uint4*)(embb + (size_t)t1 * DD + l32 * 8);
        uint4 u2 = *(const uint4*)(embb + (size_t)t2 * DD + l32 * 8);
        uint4 u3 = *(const uint4*)(embb + (size_t)t3 * DD + l32 * 8);
        const unsigned* a0 = (const unsigned*)&u0;
        const unsigned* a1 = (const unsigned*)&u1;
        const unsigned* a2 = (const unsigned*)&u2;
        const unsigned* a3 = (const unsigned*)&u3;
#pragma unroll
        for (int d = 0; d < 4; ++d) {
            acc[2*d]   += (__uint_as_float(a0[d] << 16) + __uint_as_float(a1[d] << 16))
                        + (__uint_as_float(a2[d] << 16) + __uint_as_float(a3[d] << 16));
            acc[2*d+1] += (__uint_as_float(a0[d] & 0xffff0000u) + __uint_as_float(a1[d] & 0xffff0000u))
                        + (__uint_as_float(a2[d] & 0xffff0000u) + __uint_as_float(a3[d] & 0xffff0000u));
        }
    }
    for (; i < e; i += 2) {
        int t0 = edge_tok[i];
        uint4 u = *(const uint4*)(embb + (size_t)t0 * DD + l32 * 8);
        const unsigned* ud = (const unsigned*)&u;
#pragma unroll
        for (int d = 0; d < 4; ++d) {
            acc[2*d]   += __uint_as_float(ud[d] << 16);
            acc[2*d+1] += __uint_as_float(ud[d] & 0xffff0000u);
        }
    }

#pragma unroll
    for (int j = 0; j < 8; ++j) acc[j] += __shfl_xor(acc[j], 32, 64);

    if (h == 0) {
        uint4 o;
        unsigned* od = (unsigned*)&o;
#pragma unroll
        for (int d = 0; d < 4; ++d)
            od[d] = (unsigned)f2bu(acc[2*d]) | ((unsigned)f2bu(acc[2*d+1]) << 16);
        *(uint4*)(childb + (size_t)w * DD + l32 * 8) = o;
    }
}

// ---------------------------------------------------------------------------
// Kernel 3: RNN GEMM, swapped MFMA D = W · child^T, N-SPLIT grid:
//   blockIdx.x = 128-row strip (391), blockIdx.y = col half (2) -> 782 blocks
//   (R6 had 391 -> 1.5 blocks/CU, latency exposed). Wave = 2 m-tiles.
//   W half staged in two 32KB phases (fragment order), acc persists.
//   ft written to a SEPARATE buffer (col-half blocks share rows -> in-place
//   would race with the other half's B-frag reads).
// ---------------------------------------------------------------------------
__global__ __launch_bounds__(256, 3) void rnn_mfma(
    const __hip_bfloat16* __restrict__ childb, // [M,256] child sums
    __hip_bfloat16* __restrict__ ftb,          // [M,256] out: ft
    const __hip_bfloat16* __restrict__ Wb,     // [256,256] bf16 W[n][k]
    const float* __restrict__ bvec,            // [256]
    const __hip_bfloat16* __restrict__ embb,   // [V,256] bf16
    const int* __restrict__ seg_start,
    const int* __restrict__ seg_end,
    const int* __restrict__ edge_tok,
    int M)
{
    extern __shared__ char smem[];
    __hip_bfloat16* lds = (__hip_bfloat16*)smem;   // 32KB: 32 groups of 1KB
    const int t     = threadIdx.x;
    const int lane  = t & 63;
    const int wid   = t >> 6;
    const int quad  = lane >> 4;
    const int l16   = lane & 15;
    const int mw    = blockIdx.x * 128 + wid * 32; // wave's first row
    const int nbase = blockIdx.y * 8;              // this block's first n-tile

    // per-lane row metadata + child B-frags (full K preload)
    int  mrow[2], ltok[2];
    bool multi[2];
    bf16x8 cfrag[2][8];
#pragma unroll
    for (int mt = 0; mt < 2; ++mt) {
        mrow[mt] = min(mw + mt * 16 + l16, M - 1);
        int ls = seg_start[mrow[mt]];
        int le = seg_end[mrow[mt]];
        multi[mt] = (le - ls) > 1;
        ltok[mt]  = edge_tok[le - 1];
        const __hip_bfloat16* arow = childb + (size_t)mrow[mt] * DD + quad * 8;
#pragma unroll
        for (int k0 = 0; k0 < 8; ++k0)
            cfrag[mt][k0] = *(const bf16x8*)(arow + k0 * 32);
    }

    f32x4 acc[2][8];
#pragma unroll
    for (int mt = 0; mt < 2; ++mt)
#pragma unroll
        for (int nt = 0; nt < 8; ++nt) acc[mt][nt] = (f32x4){0.f,0.f,0.f,0.f};

    for (int p = 0; p < 2; ++p) {
        if (p) __syncthreads();
        // stage 32KB: groups g = kl*8+ntl (kl in [0,4) local k0, ntl in [0,8))
#pragma unroll
        for (int it = 0; it < 8; ++it) {
            int idx = it * 256 + t;
            int g = idx >> 6, s = idx & 63;
            int ntl = g & 7, kl = g >> 3;
            int row = (nbase + ntl) * 16 + (s & 15);
            int col = (p * 4 + kl) * 32 + (s >> 4) * 8;
            *(bf16x8*)(lds + g * 512 + s * 8) =
                *(const bf16x8*)(Wb + (size_t)row * DD + col);
        }
        __syncthreads();
#pragma unroll
        for (int kl = 0; kl < 4; ++kl) {
            int k0 = p * 4 + kl;
#pragma unroll
            for (int nt = 0; nt < 8; ++nt) {
                bf16x8 wf = *(const bf16x8*)(lds + (kl * 8 + nt) * 512 + lane * 8);
                acc[0][nt] = __builtin_amdgcn_mfma_f32_16x16x32_bf16(wf, cfrag[0][k0], acc[0][nt], 0, 0, 0);
                acc[1][nt] = __builtin_amdgcn_mfma_f32_16x16x32_bf16(wf, cfrag[1][k0], acc[1][nt], 0, 0, 0);
            }
        }
    }

    // epilogue: lane owns row m, cols (nbase+nt)*16 + quad*4 + {0..3}
#pragma unroll
    for (int mt = 0; mt < 2; ++mt) {
        int m = mw + mt * 16 + l16;
        if (m < M) {
            const __hip_bfloat16* lrow = embb + (size_t)ltok[mt] * DD;
            bool mu = multi[mt];
#pragma unroll
            for (int nt = 0; nt < 8; ++nt) {
                int c0 = (nbase + nt) * 16 + quad * 4;
                float4 bia = *(const float4*)(bvec + c0);
                ushort4 lm = *(const ushort4*)(lrow + c0);
                ushort4 o;
                float v0 = mu ? fmaxf(acc[mt][nt][0] + bia.x, 0.f) : 0.f;
                float v1 = mu ? fmaxf(acc[mt][nt][1] + bia.y, 0.f) : 0.f;
                float v2 = mu ? fmaxf(acc[mt][nt][2] + bia.z, 0.f) : 0.f;
                float v3 = mu ? fmaxf(acc[mt][nt][3] + bia.w, 0.f) : 0.f;
                o.x = f2bu(v0 + bu2f(lm.x));
                o.y = f2bu(v1 + bu2f(lm.y));
                o.z = f2bu(v2 + bu2f(lm.z));
                o.w = f2bu(v3 + bu2f(lm.w));
                *(ushort4*)(ftb + (size_t)m * DD + c0) = o;
            }
        }
    }
}

// ---------------------------------------------------------------------------
// Kernel 4: classifier GEMM. 64-row blocks (782 total), wave = 1 m-tile.
// Wc (128 padded rows) staged in two 32KB K-phases, acc persists.
// ---------------------------------------------------------------------------
__global__ __launch_bounds__(256, 4) void cls_mfma(
    const __hip_bfloat16* __restrict__ ftb,    // [M,256] bf16
    const __hip_bfloat16* __restrict__ Wcb,    // [128,256] bf16 (padded)
    const float* __restrict__ bc,              // [104]
    float* __restrict__ out,                   // [M,104]
    int M)
{
    extern __shared__ char smem[];
    __hip_bfloat16* lds = (__hip_bfloat16*)smem;   // 32KB
    const int t    = threadIdx.x;
    const int lane = t & 63;
    const int wid  = t >> 6;
    const int quad = lane >> 4;
    const int l16  = lane & 15;
    const int mw   = blockIdx.x * 64 + wid * 16;

    int mrow = min(mw + l16, M - 1);
    bf16x8 ffrag[8];
    const __hip_bfloat16* arow = ftb + (size_t)mrow * DD + quad * 8;
#pragma unroll
    for (int k0 = 0; k0 < 8; ++k0)
        ffrag[k0] = *(const bf16x8*)(arow + k0 * 32);

    f32x4 acc[8];
#pragma unroll
    for (int nt = 0; nt < 8; ++nt) acc[nt] = (f32x4){0.f,0.f,0.f,0.f};

    for (int p = 0; p < 2; ++p) {
        if (p) __syncthreads();
        // stage 32KB: groups g = kl*8+nt, row = nt*16+(s&15)
#pragma unroll
        for (int it = 0; it < 8; ++it) {
            int idx = it * 256 + t;
            int g = idx >> 6, s = idx & 63;
            int nt = g & 7, kl = g >> 3;
            int row = nt * 16 + (s & 15);
            int col = (p * 4 + kl) * 32 + (s >> 4) * 8;
            *(bf16x8*)(lds + g * 512 + s * 8) =
                *(const bf16x8*)(Wcb + (size_t)row * DD + col);
        }
        __syncthreads();
#pragma unroll
        for (int kl = 0; kl < 4; ++kl) {
            int k0 = p * 4 + kl;
#pragma unroll
            for (int nt = 0; nt < 8; ++nt) {
                bf16x8 wf = *(const bf16x8*)(lds + (kl * 8 + nt) * 512 + lane * 8);
                acc[nt] = __builtin_amdgcn_mfma_f32_16x16x32_bf16(wf, ffrag[k0], acc[nt], 0, 0, 0);
            }
        }
    }

    int m = mw + l16;
    if (m < M) {
#pragma unroll
        for (int nt = 0; nt < 8; ++nt) {
            int c0 = nt * 16 + quad * 4;
            if (c0 <= 100) {
                float4 bia = *(const float4*)(bc + c0);
                float4 o;
                o.x = acc[nt][0] + bia.x;
                o.y = acc[nt][1] + bia.y;
                o.z = acc[nt][2] + bia.z;
                o.w = acc[nt][3] + bia.w;
                *(float4*)(out + (size_t)m * CC + c0) = o;
            }
        }
    }
}

// ---------------------------------------------------------------------------
extern "C" void kernel_launch(void* const* d_in, const int* in_sizes, int n_in,
                              void* d_out, int out_size, void* d_ws, size_t ws_size,
                              hipStream_t stream)
{
    const float* emb      = (const float*)d_in[0];
    const float* W        = (const float*)d_in[1];
    const float* bvec     = (const float*)d_in[2];
    const float* Wc       = (const float*)d_in[3];
    const float* bc       = (const float*)d_in[4];
    const int*   token_id = (const int*)d_in[5];
    const int*   src_idx  = (const int*)d_in[6];
    const int*   dst_idx  = (const int*)d_in[7];
    float*       out      = (float*)d_out;

    const int E     = in_sizes[6];
    const int Vemb  = in_sizes[0] / DD;
    const int n_dst = out_size / CC;
    (void)n_in; (void)ws_size;

    char* ws = (char*)d_ws;
    size_t off = 0;
    auto alloc = [&](size_t bytes) {
        void* p = ws + off;
        off = (off + bytes + 255) & ~(size_t)255;
        return p;
    };
    int* seg_start = (int*)alloc((size_t)n_dst * sizeof(int));
    int* seg_end   = (int*)alloc((size_t)n_dst * sizeof(int));
    int* edge_tok  = (int*)alloc((size_t)E * sizeof(int));
    __hip_bfloat16* childb = (__hip_bfloat16*)alloc((size_t)n_dst * DD * 2);
    __hip_bfloat16* ftb    = (__hip_bfloat16*)alloc((size_t)n_dst * DD * 2);
    __hip_bfloat16* embb   = (__hip_bfloat16*)alloc((size_t)Vemb * DD * 2);
    __hip_bfloat16* Wb     = (__hip_bfloat16*)alloc((size_t)DD * DD * 2);
    __hip_bfloat16* Wcb    = (__hip_bfloat16*)alloc((size_t)128 * DD * 2);

    const int nE4 = Vemb * (DD / 4);
    const int cvt_total   = nE4 + DD * DD / 4 + 128 * DD / 4;
    const int prep_blocks = (E + 255) / 256;
    const int cvt_blocks  = (cvt_total + 255) / 256;
    const int rnn_strips  = (n_dst + 127) / 128;
    const int cls_blocks  = (n_dst + 63) / 64;

    prep_convert_kernel<<<prep_blocks + cvt_blocks, 256, 0, stream>>>(
        token_id, src_idx, dst_idx, seg_start, seg_end, edge_tok, E,
        prep_blocks, emb, W, Wc, embb, Wb, Wcb, nE4);
    seg_sum_kernel<<<(n_dst + 3) / 4, 256, 0, stream>>>(
        embb, edge_tok, seg_start, seg_end, childb, n_dst);
    rnn_mfma<<<dim3(rnn_strips, 2), 256, 32768, stream>>>(
        childb, ftb, Wb, bvec, embb, seg_start, seg_end, edge_tok, n_dst);
    cls_mfma<<<cls_blocks, 256, 32768, stream>>>(
        ftb, Wcb, bc, out, n_dst);
}